// Round 11
// baseline (87.751 us; speedup 1.0000x reference)
//
#include <hip/hip_runtime.h>

// Bispectrum TM_b = S diag(x) S^T, fp16-split 3-pass MFMA (AhBh+AhBl+AlBh).
// Round 11: occupancy attack. R10 invariant-cost analysis => latency-bound at
// 2.5 waves/SIMD (grid 640 x 4-wave blocks, LB(256,3) self-cap). Changes:
//  - kb-split: 40 single-kb chunk-blocks/batch (was 20 kb-pairs) -> 1280
//    blocks, each wave 2 K=32 units (t=w, t=w+4). ~4+ waves/SIMD sustained.
//  - __launch_bounds__(256,4) (remove the 3-block/CU cap).
//  - reduce kernel: f32x4 loads, sums up to 8 partials per tile.
// Everything else identical to R10 (parity copy @4105 ==9 mod 32, static
// in-unit window offsets, 4-wave tree reduction, transposed mirror write).
// MFMA facts (HW-verified m89 + rounds 3/8/9/10 passing): A-row/B-col=lane&15;
// k<->slot bijection ours (k=g*8+j both sides); C/D col=lane&15,
// row=(lane>>4)*4+reg.

#define LEN 256
#define NT 8
#define F1OFF 4105      // parity copy base (odd; ==9 mod 32)
#define REDSTR 68       // reduction buffer stride
#define SMEM_DW 8704    // max(staging 4105+4096=8201, reduction 2*64*68=8704)

typedef _Float16 f16x8 __attribute__((ext_vector_type(8)));
typedef float    f32x4 __attribute__((ext_vector_type(4)));

// 40 equal-work blocks per batch: {ti, tj, kb, _}; 1 K=32 chunk each. ti>=tj.
__constant__ uchar4 kBlockTab[40] = {
    {0,0,0,0},{0,0,1,0},{0,0,2,0},{0,0,3,0},{0,0,4,0},{0,0,5,0},{0,0,6,0},{0,0,7,0},
    {1,0,2,0},{1,0,3,0},{1,0,4,0},{1,0,5,0},{1,0,6,0},{1,0,7,0},
    {1,1,2,0},{1,1,3,0},{1,1,4,0},{1,1,5,0},{1,1,6,0},{1,1,7,0},
    {2,0,4,0},{2,0,5,0},{2,0,6,0},{2,0,7,0},
    {2,1,4,0},{2,1,5,0},{2,1,6,0},{2,1,7,0},
    {2,2,4,0},{2,2,5,0},{2,2,6,0},{2,2,7,0},
    {3,0,6,0},{3,0,7,0},
    {3,1,6,0},{3,1,7,0},
    {3,2,6,0},{3,2,7,0},
    {3,3,6,0},{3,3,7,0}};
// 10 triangle tile-pairs: {ti, tj, slot_base, slot_count}
__constant__ uchar4 kPairTab[10] = {
    {0,0,0,8},{1,0,8,6},{1,1,14,6},{2,0,20,4},{2,1,24,4},{2,2,28,4},
    {3,0,32,2},{3,1,34,2},{3,2,36,2},{3,3,38,2}};

// split pair of f32 -> (hi fp16-pair bits, residual fp16-pair bits)
static __device__ __forceinline__ void split2(float a0, float a1, uint& hb, uint& lb) {
    auto h = __builtin_amdgcn_cvt_pkrtz(a0, a1);
    float e0 = a0 - (float)h[0];
    float e1 = a1 - (float)h[1];
    auto e = __builtin_amdgcn_cvt_pkrtz(e0, e1);
    __builtin_memcpy(&hb, &h, 4);
    __builtin_memcpy(&lb, &e, 4);
}
static __device__ __forceinline__ f16x8 mkf(const uint* u) {
    f16x8 v;
    __builtin_memcpy(&v, u, 16);
    return v;
}

template <bool PARTIAL>
__global__ __launch_bounds__(256, 4) void bispec_main(const float* __restrict__ x,
                                                      float* __restrict__ dst) {
    __shared__ float fs[SMEM_DW];
    const int b = blockIdx.y, bx = blockIdx.x;

    int ti, tj, kb0, kbn;
    if (PARTIAL) {
        uchar4 e = kBlockTab[bx];
        ti = e.x; tj = e.y; kb0 = e.z; kbn = 1;
    } else {
        uchar4 e = kPairTab[bx];
        ti = e.x; tj = e.y; kb0 = 2 * ti; kbn = 8 - 2 * ti;   // ti >= tj
    }
    const int l1b = ti << 6, l2b = tj << 6;
    const int tid = threadIdx.x;
    const int w = tid >> 6, l = tid & 63, cg = l & 15, g = l >> 4;

    // ---- stage padded signal: F0 @0, parity copy F1 @4105 ----
    const float* xb = x + b * (NT * LEN);
    for (int i = tid; i < 4096; i += 256) {
        int j = i & 511;
        float v = (j >= 256) ? xb[(i >> 9) * 256 + (j - 256)] : 0.0f;
        fs[i] = v;
        fs[F1OFF + i] = v;
    }
    __syncthreads();

    // Per-lane parity base: window starts are == cg (mod 2) always.
    const float* fW = fs + ((cg & 1) ? F1OFF : 0);

    f32x4 acc[4][4];
    #pragma unroll
    for (int mi = 0; mi < 4; ++mi)
        #pragma unroll
        for (int ni = 0; ni < 4; ++ni) acc[mi][ni] = 0.0f;

    #pragma unroll
    for (int tt = 0; tt < 2; ++tt) {
        const int t = w + tt * 4;              // wave w covers t = {w, w+4}
        const int xB0 = t * 512 + 256 + g * 8;

        for (int kp = 0; kp < kbn; ++kp) {     // 1 iter when PARTIAL
            const int xB = xB0 + (kb0 + kp) * 32;
            const float* pX = fs + xB;                    // 16B-aligned
            const float* pA = fW + (xB - l1b - cg - 48);  // even dword base
            const float* pB = fW + (xB - l2b - cg - 48);

            const float4 x0 = *(const float4*)(pX);
            const float4 x1 = *(const float4*)(pX + 4);
            const float xn[8] = {x0.x, x0.y, x0.z, x0.w, x1.x, x1.y, x1.z, x1.w};

            // A fragments: split(x[n] * x[n-row]); static window offsets
            f16x8 ah[4], al[4];
            #pragma unroll
            for (int mi = 0; mi < 4; ++mi) {
                const int off = 48 - mi * 16;   // compile-time, >= 0
                float wv[8];
                #pragma unroll
                for (int p = 0; p < 4; ++p) {
                    const float2 d = *(const float2*)(pA + off + 2 * p);
                    wv[2 * p] = d.x; wv[2 * p + 1] = d.y;
                }
                uint Ahp[4], Alp[4];
                #pragma unroll
                for (int p = 0; p < 4; ++p)
                    split2(xn[2 * p] * wv[2 * p], xn[2 * p + 1] * wv[2 * p + 1],
                           Ahp[p], Alp[p]);
                ah[mi] = mkf(Ahp); al[mi] = mkf(Alp);
            }

            // B fragments: split(x[n-col]); consumed per ni
            #pragma unroll
            for (int ni = 0; ni < 4; ++ni) {
                const int off = 48 - ni * 16;
                float wv[8];
                #pragma unroll
                for (int p = 0; p < 4; ++p) {
                    const float2 d = *(const float2*)(pB + off + 2 * p);
                    wv[2 * p] = d.x; wv[2 * p + 1] = d.y;
                }
                uint Bhp[4], Blp[4];
                #pragma unroll
                for (int p = 0; p < 4; ++p)
                    split2(wv[2 * p], wv[2 * p + 1], Bhp[p], Blp[p]);
                const f16x8 bh = mkf(Bhp), bl = mkf(Blp);
                #pragma unroll
                for (int mi = 0; mi < 4; ++mi) {
                    acc[mi][ni] = __builtin_amdgcn_mfma_f32_16x16x32_f16(ah[mi], bh, acc[mi][ni], 0, 0, 0);
                    acc[mi][ni] = __builtin_amdgcn_mfma_f32_16x16x32_f16(ah[mi], bl, acc[mi][ni], 0, 0, 0);
                    acc[mi][ni] = __builtin_amdgcn_mfma_f32_16x16x32_f16(al[mi], bh, acc[mi][ni], 0, 0, 0);
                }
            }
        }
    }

    // ---- cross-wave tree reduction (transposed layout, b128 LDS ops) ----
    __syncthreads();
    float* buf0 = fs;
    float* buf1 = fs + 4352;   // 64*68 = 4352
    if (w >= 2) {
        float* bb = (w == 2) ? buf0 : buf1;
        #pragma unroll
        for (int mi = 0; mi < 4; ++mi)
            #pragma unroll
            for (int ni = 0; ni < 4; ++ni)
                *(f32x4*)&bb[(ni * 16 + cg) * REDSTR + mi * 16 + g * 4] = acc[mi][ni];
    }
    __syncthreads();
    if (w < 2) {
        float* bb = (w == 0) ? buf0 : buf1;
        #pragma unroll
        for (int mi = 0; mi < 4; ++mi)
            #pragma unroll
            for (int ni = 0; ni < 4; ++ni)
                acc[mi][ni] += *(f32x4*)&bb[(ni * 16 + cg) * REDSTR + mi * 16 + g * 4];
    }
    __syncthreads();
    if (w == 1) {
        #pragma unroll
        for (int mi = 0; mi < 4; ++mi)
            #pragma unroll
            for (int ni = 0; ni < 4; ++ni)
                *(f32x4*)&buf0[(ni * 16 + cg) * REDSTR + mi * 16 + g * 4] = acc[mi][ni];
    }
    __syncthreads();
    if (w == 0) {
        #pragma unroll
        for (int mi = 0; mi < 4; ++mi)
            #pragma unroll
            for (int ni = 0; ni < 4; ++ni)
                acc[mi][ni] += *(f32x4*)&buf0[(ni * 16 + cg) * REDSTR + mi * 16 + g * 4];

        if (PARTIAL) {
            float* ob = dst + ((size_t)b * 40 + bx) * 4096;
            #pragma unroll
            for (int mi = 0; mi < 4; ++mi)
                #pragma unroll
                for (int ni = 0; ni < 4; ++ni)
                    #pragma unroll
                    for (int q = 0; q < 4; ++q)
                        ob[(mi * 16 + g * 4 + q) * 64 + ni * 16 + cg] = acc[mi][ni][q];
        } else {
            const float s = 1.0f / (float)(LEN * NT);
            float* ob = dst + (size_t)b * (LEN * LEN);
            #pragma unroll
            for (int mi = 0; mi < 4; ++mi)
                #pragma unroll
                for (int ni = 0; ni < 4; ++ni)
                    #pragma unroll
                    for (int q = 0; q < 4; ++q) {
                        const float v = acc[mi][ni][q] * s;
                        const int r = l1b + mi * 16 + g * 4 + q;
                        const int cc = l2b + ni * 16 + cg;
                        ob[(size_t)r * LEN + cc] = v;
                        if (ti != tj) ob[(size_t)cc * LEN + r] = v;
                    }
        }
    }
}

// Sum K-split partials (f32x4), scale, write tile + LDS-transposed mirror.
__global__ __launch_bounds__(256) void bispec_reduce(const float* __restrict__ ws,
                                                     float* __restrict__ out) {
    __shared__ float tile[64][65];
    const int p = blockIdx.x, b = blockIdx.y;
    uchar4 e = kPairTab[p];
    const int ii = e.x, jj = e.y, s = e.z, c = e.w;
    const float* base = ws + ((size_t)b * 40 + s) * 4096;
    float* ob = out + (size_t)b * (LEN * LEN);
    const float scale = 1.0f / (float)(LEN * NT);
    for (int k4 = threadIdx.x; k4 < 1024; k4 += 256) {
        f32x4 v = *(const f32x4*)&base[k4 * 4];
        for (int q = 1; q < c; ++q)
            v += *(const f32x4*)&base[(size_t)q * 4096 + k4 * 4];
        v *= scale;
        const int k = k4 * 4, r = k >> 6, cc = k & 63;
        tile[r][cc] = v[0]; tile[r][cc + 1] = v[1];
        tile[r][cc + 2] = v[2]; tile[r][cc + 3] = v[3];
        *(f32x4*)&ob[(size_t)(ii * 64 + r) * LEN + jj * 64 + cc] = v;
    }
    if (ii != jj) {
        __syncthreads();
        for (int k = threadIdx.x; k < 4096; k += 256) {
            const int r = k >> 6, cc = k & 63;
            ob[(size_t)(jj * 64 + r) * LEN + ii * 64 + cc] = tile[cc][r];
        }
    }
}

extern "C" void kernel_launch(void* const* d_in, const int* in_sizes, int n_in,
                              void* d_out, int out_size, void* d_ws, size_t ws_size,
                              hipStream_t stream) {
    const float* x = (const float*)d_in[0];   // [32, 8, 256] fp32
    float* out = (float*)d_out;               // [32*256*256] source ++ [32*8*256] target

    const size_t ws_need = (size_t)32 * 40 * 4096 * sizeof(float);  // 21 MB
    if (ws_size >= ws_need) {
        float* ws = (float*)d_ws;
        bispec_main<true><<<dim3(40, 32), dim3(256), 0, stream>>>(x, ws);
        bispec_reduce<<<dim3(10, 32), dim3(256), 0, stream>>>(ws, out);
    } else {
        // fallback: triangle grid, in-kernel scale + mirror (imbalanced, correct)
        bispec_main<false><<<dim3(10, 32), dim3(256), 0, stream>>>(x, out);
    }

    // Second tuple element: target passed through unchanged.
    (void)hipMemcpyAsync(out + (size_t)32 * LEN * LEN, x,
                         (size_t)32 * NT * LEN * sizeof(float),
                         hipMemcpyDeviceToDevice, stream);
}

// Round 12
// 84.711 us; speedup vs baseline: 1.0359x; 1.0359x over previous
//
#include <hip/hip_runtime.h>

// Bispectrum TM_b = S diag(x) S^T, fp16-split 3-pass MFMA (AhBh+AhBl+AlBh).
// Round 12: VGPR diet -> 8 waves/SIMD. m69: occupancy steps at VGPR 64/128/256,
// so the old 4x4-fragment design (acc=64 VGPR alone, total ~96-104) was pinned
// at 4 waves/SIMD forever. New structure:
//  - each wave owns a 32x32 QUARTER of the 64x64 tile (2x2 frags, acc=16 VGPR),
//    loops all 8 t -> no cross-wave reduction, no epilogue barriers.
//  - single LDS staging copy (16.4 KB, was 34.8); window reads = 8x ds_read_b32
//    (arbitrary parity, no parity copy needed).
//  - __launch_bounds__(256,8): cap VGPR at 64 -> 8 waves/SIMD.
// Work split: 40 equal chunk-blocks/batch (triangle + zero-skip, kbn=1),
// partials to d_ws, reduce kernel sums + mirrors (unchanged from R11).
// MFMA facts (HW-verified m89 + rounds 3/8-11 passing): A-row/B-col = lane&15;
// k<->slot bijection ours (k=g*8+j both sides); C/D col=lane&15,
// row=(lane>>4)*4+reg.

#define LEN 256
#define NT 8
#define SMEM_DW 4104

typedef _Float16 f16x8 __attribute__((ext_vector_type(8)));
typedef float    f32x4 __attribute__((ext_vector_type(4)));

// 40 equal-work blocks per batch: {ti, tj, kb, _}; 1 K=32 chunk each. ti>=tj.
__constant__ uchar4 kBlockTab[40] = {
    {0,0,0,0},{0,0,1,0},{0,0,2,0},{0,0,3,0},{0,0,4,0},{0,0,5,0},{0,0,6,0},{0,0,7,0},
    {1,0,2,0},{1,0,3,0},{1,0,4,0},{1,0,5,0},{1,0,6,0},{1,0,7,0},
    {1,1,2,0},{1,1,3,0},{1,1,4,0},{1,1,5,0},{1,1,6,0},{1,1,7,0},
    {2,0,4,0},{2,0,5,0},{2,0,6,0},{2,0,7,0},
    {2,1,4,0},{2,1,5,0},{2,1,6,0},{2,1,7,0},
    {2,2,4,0},{2,2,5,0},{2,2,6,0},{2,2,7,0},
    {3,0,6,0},{3,0,7,0},
    {3,1,6,0},{3,1,7,0},
    {3,2,6,0},{3,2,7,0},
    {3,3,6,0},{3,3,7,0}};
// 10 triangle tile-pairs: {ti, tj, slot_base, slot_count}
__constant__ uchar4 kPairTab[10] = {
    {0,0,0,8},{1,0,8,6},{1,1,14,6},{2,0,20,4},{2,1,24,4},{2,2,28,4},
    {3,0,32,2},{3,1,34,2},{3,2,36,2},{3,3,38,2}};

// split pair of f32 -> (hi fp16-pair bits, residual fp16-pair bits)
static __device__ __forceinline__ void split2(float a0, float a1, uint& hb, uint& lb) {
    auto h = __builtin_amdgcn_cvt_pkrtz(a0, a1);
    float e0 = a0 - (float)h[0];
    float e1 = a1 - (float)h[1];
    auto e = __builtin_amdgcn_cvt_pkrtz(e0, e1);
    __builtin_memcpy(&hb, &h, 4);
    __builtin_memcpy(&lb, &e, 4);
}
static __device__ __forceinline__ f16x8 mkf(const uint* u) {
    f16x8 v;
    __builtin_memcpy(&v, u, 16);
    return v;
}

template <bool PARTIAL>
__global__ __launch_bounds__(256, 8) void bispec_main(const float* __restrict__ x,
                                                      float* __restrict__ dst) {
    __shared__ float fs[SMEM_DW];
    const int b = blockIdx.y, bx = blockIdx.x;

    int ti, tj, kb0, kbn;
    if (PARTIAL) {
        uchar4 e = kBlockTab[bx];
        ti = e.x; tj = e.y; kb0 = e.z; kbn = 1;
    } else {
        uchar4 e = kPairTab[bx];
        ti = e.x; tj = e.y; kb0 = 2 * ti; kbn = 8 - 2 * ti;   // ti >= tj
    }
    const int l1b = ti << 6, l2b = tj << 6;
    const int tid = threadIdx.x;
    const int w = tid >> 6, l = tid & 63, cg = l & 15, g = l >> 4;
    const int qr = (w >> 1) << 5, qc = (w & 1) << 5;   // wave's 32x32 quarter

    // ---- stage padded signal, single copy ----
    const float* xb = x + b * (NT * LEN);
    for (int i = tid; i < 4096; i += 256) {
        int j = i & 511;
        fs[i] = (j >= 256) ? xb[(i >> 9) * 256 + (j - 256)] : 0.0f;
    }
    __syncthreads();

    f32x4 acc[2][2];
    #pragma unroll
    for (int mi = 0; mi < 2; ++mi)
        #pragma unroll
        for (int ni = 0; ni < 2; ++ni) acc[mi][ni] = 0.0f;

    for (int kp = 0; kp < kbn; ++kp) {       // 1 iter when PARTIAL
        const int kb = kb0 + kp;
        #pragma unroll 2
        for (int t = 0; t < NT; ++t) {
            const int xB = t * 512 + 256 + g * 8 + kb * 32;
            const float4 x0 = *(const float4*)&fs[xB];
            const float4 x1 = *(const float4*)&fs[xB + 4];
            const float xn[8] = {x0.x, x0.y, x0.z, x0.w, x1.x, x1.y, x1.z, x1.w};

            // A fragments for this wave's 2 row-blocks
            f16x8 ah[2], al[2];
            #pragma unroll
            for (int mi = 0; mi < 2; ++mi) {
                const int p0 = xB - l1b - qr - mi * 16 - cg;
                float wv[8];
                #pragma unroll
                for (int p = 0; p < 8; ++p) wv[p] = fs[p0 + p];
                uint Ahp[4], Alp[4];
                #pragma unroll
                for (int p = 0; p < 4; ++p)
                    split2(xn[2 * p] * wv[2 * p], xn[2 * p + 1] * wv[2 * p + 1],
                           Ahp[p], Alp[p]);
                ah[mi] = mkf(Ahp); al[mi] = mkf(Alp);
            }

            // B fragments for this wave's 2 col-blocks; consumed immediately
            #pragma unroll
            for (int ni = 0; ni < 2; ++ni) {
                const int p0 = xB - l2b - qc - ni * 16 - cg;
                float wv[8];
                #pragma unroll
                for (int p = 0; p < 8; ++p) wv[p] = fs[p0 + p];
                uint Bhp[4], Blp[4];
                #pragma unroll
                for (int p = 0; p < 4; ++p)
                    split2(wv[2 * p], wv[2 * p + 1], Bhp[p], Blp[p]);
                const f16x8 bh = mkf(Bhp), bl = mkf(Blp);
                #pragma unroll
                for (int mi = 0; mi < 2; ++mi) {
                    acc[mi][ni] = __builtin_amdgcn_mfma_f32_16x16x32_f16(ah[mi], bh, acc[mi][ni], 0, 0, 0);
                    acc[mi][ni] = __builtin_amdgcn_mfma_f32_16x16x32_f16(ah[mi], bl, acc[mi][ni], 0, 0, 0);
                    acc[mi][ni] = __builtin_amdgcn_mfma_f32_16x16x32_f16(al[mi], bh, acc[mi][ni], 0, 0, 0);
                }
            }
        }
    }

    // ---- epilogue: each wave writes its own quarter (no cross-wave reduce) ----
    if (PARTIAL) {
        float* ob = dst + ((size_t)b * 40 + bx) * 4096;
        #pragma unroll
        for (int mi = 0; mi < 2; ++mi)
            #pragma unroll
            for (int ni = 0; ni < 2; ++ni)
                #pragma unroll
                for (int q = 0; q < 4; ++q)
                    ob[(qr + mi * 16 + g * 4 + q) * 64 + qc + ni * 16 + cg] = acc[mi][ni][q];
    } else {
        const float s = 1.0f / (float)(LEN * NT);
        float* ob = dst + (size_t)b * (LEN * LEN);
        #pragma unroll
        for (int mi = 0; mi < 2; ++mi)
            #pragma unroll
            for (int ni = 0; ni < 2; ++ni)
                #pragma unroll
                for (int q = 0; q < 4; ++q) {
                    const float v = acc[mi][ni][q] * s;
                    const int r = l1b + qr + mi * 16 + g * 4 + q;
                    const int cc = l2b + qc + ni * 16 + cg;
                    ob[(size_t)r * LEN + cc] = v;
                    if (ti != tj) ob[(size_t)cc * LEN + r] = v;
                }
    }
}

// Sum K-split partials (f32x4), scale, write tile + LDS-transposed mirror.
__global__ __launch_bounds__(256) void bispec_reduce(const float* __restrict__ ws,
                                                     float* __restrict__ out) {
    __shared__ float tile[64][65];
    const int p = blockIdx.x, b = blockIdx.y;
    uchar4 e = kPairTab[p];
    const int ii = e.x, jj = e.y, s = e.z, c = e.w;
    const float* base = ws + ((size_t)b * 40 + s) * 4096;
    float* ob = out + (size_t)b * (LEN * LEN);
    const float scale = 1.0f / (float)(LEN * NT);
    for (int k4 = threadIdx.x; k4 < 1024; k4 += 256) {
        f32x4 v = *(const f32x4*)&base[k4 * 4];
        for (int q = 1; q < c; ++q)
            v += *(const f32x4*)&base[(size_t)q * 4096 + k4 * 4];
        v *= scale;
        const int k = k4 * 4, r = k >> 6, cc = k & 63;
        tile[r][cc] = v[0]; tile[r][cc + 1] = v[1];
        tile[r][cc + 2] = v[2]; tile[r][cc + 3] = v[3];
        *(f32x4*)&ob[(size_t)(ii * 64 + r) * LEN + jj * 64 + cc] = v;
    }
    if (ii != jj) {
        __syncthreads();
        for (int k = threadIdx.x; k < 4096; k += 256) {
            const int r = k >> 6, cc = k & 63;
            ob[(size_t)(jj * 64 + r) * LEN + ii * 64 + cc] = tile[cc][r];
        }
    }
}

extern "C" void kernel_launch(void* const* d_in, const int* in_sizes, int n_in,
                              void* d_out, int out_size, void* d_ws, size_t ws_size,
                              hipStream_t stream) {
    const float* x = (const float*)d_in[0];   // [32, 8, 256] fp32
    float* out = (float*)d_out;               // [32*256*256] source ++ [32*8*256] target

    const size_t ws_need = (size_t)32 * 40 * 4096 * sizeof(float);  // 21 MB
    if (ws_size >= ws_need) {
        float* ws = (float*)d_ws;
        bispec_main<true><<<dim3(40, 32), dim3(256), 0, stream>>>(x, ws);
        bispec_reduce<<<dim3(10, 32), dim3(256), 0, stream>>>(ws, out);
    } else {
        // fallback: triangle grid, in-kernel scale + mirror (imbalanced, correct)
        bispec_main<false><<<dim3(10, 32), dim3(256), 0, stream>>>(x, out);
    }

    // Second tuple element: target passed through unchanged.
    (void)hipMemcpyAsync(out + (size_t)32 * LEN * LEN, x,
                         (size_t)32 * NT * LEN * sizeof(float),
                         hipMemcpyDeviceToDevice, stream);
}